// Round 9
// baseline (800.729 us; speedup 1.0000x reference)
//
#include <hip/hip_runtime.h>

#define HEADS 4
#define CH 64
#define HC 256
#define NGRAPH 32
#define NEG_ATT 0.2f
#define NEG_ACT 0.01f

typedef __attribute__((ext_vector_type(8))) short bf16x8;
typedef __attribute__((ext_vector_type(4))) float f32x4;
typedef __attribute__((ext_vector_type(2))) float f32x2;

typedef __attribute__((address_space(3))) unsigned int lds_u32;
typedef const __attribute__((address_space(1))) unsigned int glob_u32;

// async global->LDS, 16B per lane; LDS dest = wave-uniform base + lane*16
__device__ __forceinline__ void gl_lds16(const void* g, void* l) {
  __builtin_amdgcn_global_load_lds((glob_u32*)(uintptr_t)g,
                                   (lds_u32*)(unsigned int)(uintptr_t)l, 16, 0, 0);
}

// split two fp32 into packed hi-bf16 pair and lo-bf16 pair (truncation; lo captures residual)
__device__ __forceinline__ void split2(float a, float b, unsigned& hi, unsigned& lo) {
  unsigned ua = __float_as_uint(a), ub = __float_as_uint(b);
  float la = a - __uint_as_float(ua & 0xFFFF0000u);
  float lb = b - __uint_as_float(ub & 0xFFFF0000u);
  hi = __builtin_amdgcn_perm(ub, ua, 0x07060302u);  // [hi16(b) : hi16(a)]
  lo = __builtin_amdgcn_perm(__float_as_uint(lb), __float_as_uint(la), 0x07060302u);
}

// round-to-nearest-even fp32 -> bf16 (low 16 bits)
__device__ __forceinline__ unsigned rtn_bf16(float f) {
  unsigned u = __float_as_uint(f);
  return (u + 0x7FFFu + ((u >> 16) & 1u)) >> 16;
}
__device__ __forceinline__ unsigned rtn_pack2(float a, float b) {
  return (rtn_bf16(b) << 16) | rtn_bf16(a);
}

// ---------- conversions ----------
__global__ __launch_bounds__(256) void convert_x(
    const float* __restrict__ X, unsigned short* __restrict__ xhi,
    unsigned short* __restrict__ xlo, int total4) {
  int g = blockIdx.x * 256 + threadIdx.x;
  if (g >= total4) return;
  float4 v = *(const float4*)&X[(size_t)g * 4];
  uint2 h2, l2;
  split2(v.x, v.y, h2.x, l2.x);
  split2(v.z, v.w, h2.y, l2.y);
  *(uint2*)&xhi[(size_t)g * 4] = h2;
  *(uint2*)&xlo[(size_t)g * 4] = l2;
}

// All three W' = [Wl; Wr] (512 x K) -> MFMA-fragment-ordered hi/lo planes, one dispatch.
// Per layer: chunk ci = (kb*32 + ct)*64 + lane holds W'[ct*16+(lane&15)][kb*32+(lane>>4)*8..+8]
__device__ __forceinline__ void conv_w_one(
    int g, const float* Wl, const float* Wr, int K,
    unsigned short* wfhi, unsigned short* wflo) {
  int lane = g & 63;
  int ct = (g >> 6) & 31;
  int kb = g >> 11;
  int col = ct * 16 + (lane & 15);
  int k = kb * 32 + (lane >> 4) * 8;
  const float* src = (col < HC) ? &Wl[(size_t)col * K + k] : &Wr[(size_t)(col - HC) * K + k];
  float4 v0 = *(const float4*)src;
  float4 v1 = *(const float4*)(src + 4);
  uint4 hq, lq;
  split2(v0.x, v0.y, hq.x, lq.x);
  split2(v0.z, v0.w, hq.y, lq.y);
  split2(v1.x, v1.y, hq.z, lq.z);
  split2(v1.z, v1.w, hq.w, lq.w);
  *(uint4*)&wfhi[(size_t)g * 8] = hq;
  *(uint4*)&wflo[(size_t)g * 8] = lq;
}

__global__ __launch_bounds__(256) void convert_w_all(
    const float* __restrict__ Wl1, const float* __restrict__ Wr1,
    unsigned short* __restrict__ w1hi, unsigned short* __restrict__ w1lo,
    const float* __restrict__ Wl2, const float* __restrict__ Wr2,
    unsigned short* __restrict__ w2hi, unsigned short* __restrict__ w2lo,
    const float* __restrict__ Wl3, const float* __restrict__ Wr3,
    unsigned short* __restrict__ w3hi, unsigned short* __restrict__ w3lo) {
  int g = blockIdx.x * 256 + threadIdx.x;
  // layer1: 128*64 = 8192 chunks; layers 2,3: 16384 each
  if (g < 8192) conv_w_one(g, Wl1, Wr1, 128, w1hi, w1lo);
  else if (g < 8192 + 16384) conv_w_one(g - 8192, Wl2, Wr2, 256, w2hi, w2lo);
  else conv_w_one(g - 8192 - 16384, Wl3, Wr3, 256, w3hi, w3lo);
}

// ---------- MFMA GEMM: [xl(bf16) | xr(bf16)] = X(hi/lo) @ W'(hi/lo)^T + bias ----------
// 128x128 per block (XCD-swizzled flat grid), 4 waves. A: double-buffered LDS via
// global_load_lds. B: fragment-ordered global loads (L2-resident). 3-term split-bf16.
template <int K>
__global__ __launch_bounds__(256) void gemm_fused(
    const unsigned short* __restrict__ xhi, const unsigned short* __restrict__ xlo,
    const unsigned short* __restrict__ wfhi, const unsigned short* __restrict__ wflo,
    const float* __restrict__ bl, const float* __restrict__ br,
    unsigned short* __restrict__ Y1, unsigned short* __restrict__ Y2, int N, int nrb) {
  constexpr int nkb = K >> 5;
  __shared__ unsigned short Ah[2][128][32];
  __shared__ unsigned short Al[2][128][32];

  // XCD swizzle: f = (rb%8) + 8*(cb + 4*(rb/8)) -> 4 col-siblings land on one XCD
  const int f = blockIdx.x;
  const int rb = (f & 7) + 8 * (f >> 5);
  const int cb = (f >> 3) & 3;
  if (rb >= nrb) return;

  const int tid = threadIdx.x;
  const int wave = tid >> 6;
  const int lane = tid & 63;
  const int quad = lane >> 4;
  const int l16 = lane & 15;
  const int wr = (wave >> 1) * 64;
  const int wc = (wave & 1) * 64;
  const int row0 = rb * 128;
  const int col0 = cb * 128;
  const int ctg0 = cb * 8 + (wave & 1) * 4;

  // staging addresses for this thread (2 chunks per plane)
  const int c0 = tid, c1 = tid + 256;
  const int r0g = row0 + (c0 >> 2), r1g = row0 + (c1 >> 2);
  const int ko0 = (c0 & 3) * 8, ko1 = (c1 & 3) * 8;
  const int gr0 = (r0g < N) ? r0g : N - 1;
  const int gr1 = (r1g < N) ? r1g : N - 1;

  f32x4 acc[4][4];
#pragma unroll
  for (int i = 0; i < 4; i++)
#pragma unroll
    for (int j = 0; j < 4; j++) acc[i][j] = (f32x4){0.f, 0.f, 0.f, 0.f};

  // prologue: stage k-tile 0 into buffer 0
  {
    size_t ga0 = (size_t)gr0 * K + ko0;
    size_t ga1 = (size_t)gr1 * K + ko1;
    gl_lds16(&xhi[ga0], &Ah[0][c0 >> 2][ko0]);
    gl_lds16(&xlo[ga0], &Al[0][c0 >> 2][ko0]);
    gl_lds16(&xhi[ga1], &Ah[0][c1 >> 2][ko1]);
    gl_lds16(&xlo[ga1], &Al[0][c1 >> 2][ko1]);
  }

#pragma unroll
  for (int kb = 0; kb < nkb; kb++) {
    const int cur = kb & 1, nxt = cur ^ 1;
    // B fragments for this k-tile (global, L2-resident, coalesced 16B/lane)
    bf16x8 bhi[4], blo[4];
#pragma unroll
    for (int j = 0; j < 4; j++) {
      size_t ci = ((size_t)kb * 32 + ctg0 + j) * 64 + lane;
      bhi[j] = *(const bf16x8*)&wfhi[ci * 8];
      blo[j] = *(const bf16x8*)&wflo[ci * 8];
    }
    __syncthreads();  // drains staging(kb) into cur
    if (kb + 1 < nkb) {
      int k0 = (kb + 1) * 32;
      size_t ga0 = (size_t)gr0 * K + k0 + ko0;
      size_t ga1 = (size_t)gr1 * K + k0 + ko1;
      gl_lds16(&xhi[ga0], &Ah[nxt][c0 >> 2][ko0]);
      gl_lds16(&xlo[ga0], &Al[nxt][c0 >> 2][ko0]);
      gl_lds16(&xhi[ga1], &Ah[nxt][c1 >> 2][ko1]);
      gl_lds16(&xlo[ga1], &Al[nxt][c1 >> 2][ko1]);
    }
    bf16x8 ahi[4], alo[4];
#pragma unroll
    for (int i = 0; i < 4; i++) {
      ahi[i] = *(const bf16x8*)&Ah[cur][wr + i * 16 + l16][quad * 8];
      alo[i] = *(const bf16x8*)&Al[cur][wr + i * 16 + l16][quad * 8];
    }
#pragma unroll
    for (int i = 0; i < 4; i++)
#pragma unroll
      for (int j = 0; j < 4; j++) {
        acc[i][j] = __builtin_amdgcn_mfma_f32_16x16x32_bf16(ahi[i], bhi[j], acc[i][j], 0, 0, 0);
        acc[i][j] = __builtin_amdgcn_mfma_f32_16x16x32_bf16(ahi[i], blo[j], acc[i][j], 0, 0, 0);
        acc[i][j] = __builtin_amdgcn_mfma_f32_16x16x32_bf16(alo[i], bhi[j], acc[i][j], 0, 0, 0);
      }
  }

  // epilogue: D row = quad*4+reg, col = l16; both halves -> bf16 (RTN)
#pragma unroll
  for (int j = 0; j < 4; j++) {
    int colg = col0 + wc + j * 16 + l16;  // 0..511
    unsigned short* Yp = (colg < HC) ? Y1 : Y2;
    int cc = (colg < HC) ? colg : colg - HC;
    float bv = (colg < HC) ? bl[cc] : br[cc];
#pragma unroll
    for (int i = 0; i < 4; i++)
#pragma unroll
      for (int r = 0; r < 4; r++) {
        int row = row0 + wr + i * 16 + quad * 4 + r;
        if (row < N)
          Yp[(size_t)row * HC + cc] = (unsigned short)rtn_bf16(acc[i][j][r] + bv);
      }
  }
}

// ---------- CSR build (csr_src holds BYTE offsets into bf16 xl: src*512) ----------
__global__ __launch_bounds__(256) void hist_dst(
    const int* __restrict__ edst, int* __restrict__ counts, int E) {
  int e = blockIdx.x * 256 + threadIdx.x;
  if (e < E) atomicAdd(&counts[edst[e]], 1);
}

__global__ __launch_bounds__(256) void scan_blocks(
    const int* __restrict__ counts, int* __restrict__ row_start,
    int* __restrict__ bsum, int N) {
  __shared__ int tmp[256];
  int t = threadIdx.x;
  int base = blockIdx.x * 1024 + t * 4;
  int v0 = (base     < N) ? counts[base]     + 1 : 0;
  int v1 = (base + 1 < N) ? counts[base + 1] + 1 : 0;
  int v2 = (base + 2 < N) ? counts[base + 2] + 1 : 0;
  int v3 = (base + 3 < N) ? counts[base + 3] + 1 : 0;
  int c1 = v0 + v1, c2 = c1 + v2, tot = c2 + v3;
  tmp[t] = tot;
  __syncthreads();
  for (int off = 1; off < 256; off <<= 1) {
    int add = (t >= off) ? tmp[t - off] : 0;
    __syncthreads();
    tmp[t] += add;
    __syncthreads();
  }
  int excl = tmp[t] - tot;
  if (base     < N) row_start[base + 1] = excl + v0;
  if (base + 1 < N) row_start[base + 2] = excl + c1;
  if (base + 2 < N) row_start[base + 3] = excl + c2;
  if (base + 3 < N) row_start[base + 4] = excl + tot;
  if (t == 255) bsum[blockIdx.x] = tmp[255];
  if (blockIdx.x == 0 && t == 0) row_start[0] = 0;
}

__global__ void scan_tops(int* __restrict__ bsum, int nb) {
  int lane = threadIdx.x;
  int v = (lane < nb) ? bsum[lane] : 0;
  for (int off = 1; off < 64; off <<= 1) {
    int u = __shfl_up(v, off);
    if (lane >= off) v += u;
  }
  if (lane < nb) bsum[lane] = v;
}

__global__ __launch_bounds__(256) void scan_add(
    int* __restrict__ row_start, const int* __restrict__ bsum, int N) {
  int off = bsum[blockIdx.x];
  int i = (blockIdx.x + 1) * 1024 + threadIdx.x * 4;
#pragma unroll
  for (int k = 0; k < 4; k++)
    if (i + k < N) row_start[i + k + 1] += off;
}

__global__ __launch_bounds__(256) void csr_init(
    const int* __restrict__ row_start, int* __restrict__ fill_pos,
    int* __restrict__ csr_src, int N) {
  int i = blockIdx.x * 256 + threadIdx.x;
  if (i < N) {
    int p = row_start[i];
    csr_src[p] = i << 9;  // self-loop first, byte offset
    fill_pos[i] = p + 1;
  }
}

__global__ __launch_bounds__(256) void csr_scatter(
    const int* __restrict__ esrc, const int* __restrict__ edst,
    int* __restrict__ fill_pos, int* __restrict__ csr_src, int E) {
  int e = blockIdx.x * 256 + threadIdx.x;
  if (e < E) {
    int p = atomicAdd(&fill_pos[edst[e]], 1);
    csr_src[p] = esrc[e] << 9;  // byte offset
  }
}

// ---------- fused GATv2 edge phase: raw-exp softmax (scores bounded), packed f32 ----------
__device__ __forceinline__ void unpk(uint2 q, f32x2& v01, f32x2& v23) {
  v01.x = __uint_as_float(q.x << 16);
  v01.y = __uint_as_float(q.x & 0xFFFF0000u);
  v23.x = __uint_as_float(q.y << 16);
  v23.y = __uint_as_float(q.y & 0xFFFF0000u);
}

__device__ __forceinline__ float edot(f32x2 l01, f32x2 l23, f32x2 r01, f32x2 r23,
                                      f32x2 a01, f32x2 a23) {
  f32x2 t01 = l01 + r01, t23 = l23 + r23;          // v_pk_add_f32
  f32x2 u01 = t01 * NEG_ATT, u23 = t23 * NEG_ATT;  // v_pk_mul_f32
  t01.x = fmaxf(t01.x, u01.x); t01.y = fmaxf(t01.y, u01.y);  // leaky = max(t,0.2t)
  t23.x = fmaxf(t23.x, u23.x); t23.y = fmaxf(t23.y, u23.y);
  f32x2 dv = t01 * a01 + t23 * a23;                // pk_mul + pk_fma
  float d = dv.x + dv.y;
  d += __shfl_xor(d, 1);
  d += __shfl_xor(d, 2);
  d += __shfl_xor(d, 4);
  d += __shfl_xor(d, 8);
  return d;
}

// mode 1: leaky + split to hi/lo planes (layers 1,2). mode 2: bf16 RTN out (layer 3).
__global__ __launch_bounds__(256) void gat_fused(
    const unsigned short* __restrict__ xl, const unsigned short* __restrict__ xr,
    const int* __restrict__ row_start, const int* __restrict__ csr_soff,
    const float* __restrict__ att, const float* __restrict__ bo,
    unsigned short* __restrict__ ohi, unsigned short* __restrict__ olo,
    int N, int mode) {
  int dst = (blockIdx.x * 256 + threadIdx.x) >> 6;
  int lane = threadIdx.x & 63;
  if (dst >= N) return;
  int h = lane >> 4;
  int off = h * CH + (lane & 15) * 4;
  const int loff = off * 2;  // byte offset of this lane's 4 bf16 channels
  const char* xlc = (const char*)xl;
  f32x2 a01 = *(const f32x2*)&att[off];
  f32x2 a23 = *(const f32x2*)&att[off + 2];
  f32x2 r01, r23;
  unpk(*(const uint2*)&xr[(size_t)dst * HC + off], r01, r23);
  f32x2 o01 = {0.f, 0.f}, o23 = {0.f, 0.f};
  float s = 0.f;
  int p = row_start[dst];
  int end = row_start[dst + 1];
  for (; p + 4 <= end; p += 4) {
    int b0 = csr_soff[p + 0] + loff, b1 = csr_soff[p + 1] + loff;
    int b2 = csr_soff[p + 2] + loff, b3 = csr_soff[p + 3] + loff;
    uint2 q0 = *(const uint2*)(xlc + b0);
    uint2 q1 = *(const uint2*)(xlc + b1);
    uint2 q2 = *(const uint2*)(xlc + b2);
    uint2 q3 = *(const uint2*)(xlc + b3);
    f32x2 l0a, l0b, l1a, l1b, l2a, l2b, l3a, l3b;
    unpk(q0, l0a, l0b);
    unpk(q1, l1a, l1b);
    unpk(q2, l2a, l2b);
    unpk(q3, l3a, l3b);
    float e0 = __expf(edot(l0a, l0b, r01, r23, a01, a23));
    float e1 = __expf(edot(l1a, l1b, r01, r23, a01, a23));
    float e2 = __expf(edot(l2a, l2b, r01, r23, a01, a23));
    float e3 = __expf(edot(l3a, l3b, r01, r23, a01, a23));
    s += (e0 + e1) + (e2 + e3);
    o01 = l0a * e0 + o01;
    o01 = l1a * e1 + o01;
    o01 = l2a * e2 + o01;
    o01 = l3a * e3 + o01;
    o23 = l0b * e0 + o23;
    o23 = l1b * e1 + o23;
    o23 = l2b * e2 + o23;
    o23 = l3b * e3 + o23;
  }
  for (; p < end; p++) {
    int b0 = csr_soff[p] + loff;
    uint2 q0 = *(const uint2*)(xlc + b0);
    f32x2 la, lb;
    unpk(q0, la, lb);
    float pe = __expf(edot(la, lb, r01, r23, a01, a23));
    s += pe;
    o01 = la * pe + o01;
    o23 = lb * pe + o23;
  }
  float inv = 1.f / s;
  f32x2 b01 = *(const f32x2*)&bo[off];
  f32x2 b23 = *(const f32x2*)&bo[off + 2];
  f32x2 res01 = o01 * inv + b01;
  f32x2 res23 = o23 * inv + b23;
  if (mode == 1) {
    f32x2 v01 = res01 * NEG_ACT, v23 = res23 * NEG_ACT;
    res01.x = fmaxf(res01.x, v01.x); res01.y = fmaxf(res01.y, v01.y);
    res23.x = fmaxf(res23.x, v23.x); res23.y = fmaxf(res23.y, v23.y);
    uint2 h2, l2;
    split2(res01.x, res01.y, h2.x, l2.x);
    split2(res23.x, res23.y, h2.y, l2.y);
    *(uint2*)&ohi[(size_t)dst * HC + off] = h2;
    *(uint2*)&olo[(size_t)dst * HC + off] = l2;
  } else {
    uint2 pk;
    pk.x = rtn_pack2(res01.x, res01.y);
    pk.y = rtn_pack2(res23.x, res23.y);
    *(uint2*)&ohi[(size_t)dst * HC + off] = pk;
  }
}

// ---------- pooling: one block per graph, sorted batch -> binary-search bounds ----------
__global__ __launch_bounds__(256) void pool_direct(
    const unsigned short* __restrict__ h3, const int* __restrict__ batch,
    float* __restrict__ out, int N) {
  const int g = blockIdx.x;
  const int t = threadIdx.x;
  // lower_bound(batch, g) and lower_bound(batch, g+1)
  int lo = 0, hi = N;
  while (lo < hi) { int mid = (lo + hi) >> 1; if (batch[mid] < g) lo = mid + 1; else hi = mid; }
  int lo2 = lo, hi2 = N;
  while (lo2 < hi2) { int mid = (lo2 + hi2) >> 1; if (batch[mid] < g + 1) lo2 = mid + 1; else hi2 = mid; }
  const int cnt = lo2 - lo;
  const int colu = t & 127;   // uint column (2 channels)
  const int rpar = t >> 7;    // row parity
  f32x2 acc = {0.f, 0.f};
  const unsigned* h3u = (const unsigned*)h3;
  for (int n = lo + rpar; n < lo2; n += 2) {
    unsigned q = h3u[(size_t)n * 128 + colu];
    f32x2 v;
    v.x = __uint_as_float(q << 16);
    v.y = __uint_as_float(q & 0xFFFF0000u);
    acc += v;
  }
  __shared__ f32x2 sh[2][128];
  sh[rpar][colu] = acc;
  __syncthreads();
  if (t < 128) {
    f32x2 tot = sh[0][t] + sh[1][t];
    float c = (float)max(cnt, 1);
    f32x2 res = tot * (1.f / c);
    *(f32x2*)&out[g * HC + t * 2] = res;
  }
}

extern "C" void kernel_launch(void* const* d_in, const int* in_sizes, int n_in,
                              void* d_out, int out_size, void* d_ws, size_t ws_size,
                              hipStream_t stream) {
  const float* x = (const float*)d_in[0];
  const int* ei = (const int*)d_in[1];
  const int* batch = (const int*)d_in[2];
  const int N = in_sizes[2];
  const int E = in_sizes[1] / 2;
  const int Etot = E + N;

  const float* Wl[3] = {(const float*)d_in[3], (const float*)d_in[9], (const float*)d_in[15]};
  const float* bl[3] = {(const float*)d_in[4], (const float*)d_in[10], (const float*)d_in[16]};
  const float* Wr[3] = {(const float*)d_in[5], (const float*)d_in[11], (const float*)d_in[17]};
  const float* br[3] = {(const float*)d_in[6], (const float*)d_in[12], (const float*)d_in[18]};
  const float* att[3] = {(const float*)d_in[7], (const float*)d_in[13], (const float*)d_in[19]};
  const float* bo[3] = {(const float*)d_in[8], (const float*)d_in[14], (const float*)d_in[20]};

  // ws layout
  float* B0 = (float*)d_ws;                 // input planes (all layers) / h3 bf16 (layer 3 out)
  float* B1 = B0 + (size_t)N * HC;          // xl (bf16, half the slot)
  float* B2 = B1 + (size_t)N * HC;          // xr (bf16, half the slot)
  unsigned short* w1hi = (unsigned short*)(B2 + (size_t)N * HC);
  unsigned short* w1lo = w1hi + 512 * 128;
  unsigned short* w2hi = w1lo + 512 * 128;
  unsigned short* w2lo = w2hi + 512 * 256;
  unsigned short* w3hi = w2lo + 512 * 256;
  unsigned short* w3lo = w3hi + 512 * 256;
  int* counts = (int*)(w3lo + 512 * 256);
  int* row_start = counts + N;
  int* bsum = row_start + N + 1;
  int* fill_pos = bsum + 64;
  int* csr_src = fill_pos + N;

  unsigned short* xlB = (unsigned short*)B1;
  unsigned short* xrB = (unsigned short*)B2;
  unsigned short* xhiL1 = (unsigned short*)B0;
  unsigned short* xloL1 = xhiL1 + (size_t)N * 128;
  unsigned short* xhiL = (unsigned short*)B0;
  unsigned short* xloL = xhiL + (size_t)N * HC;
  unsigned short* h3B = (unsigned short*)B0;  // layer-3 gat output (planes dead by then)

  const int* esrc = ei;
  const int* edst = ei + E;

  // ---- conversions (2 dispatches) ----
  convert_x<<<(N * 128 / 4 + 255) / 256, 256, 0, stream>>>(x, xhiL1, xloL1, N * 128 / 4);
  convert_w_all<<<(8192 + 16384 + 16384) / 256, 256, 0, stream>>>(
      Wl[0], Wr[0], w1hi, w1lo, Wl[1], Wr[1], w2hi, w2lo, Wl[2], Wr[2], w3hi, w3lo);

  // ---- CSR build ----
  const int nscan = (N + 1023) / 1024;
  (void)hipMemsetAsync(counts, 0, (size_t)N * sizeof(int), stream);
  hist_dst<<<(E + 255) / 256, 256, 0, stream>>>(edst, counts, E);
  scan_blocks<<<nscan, 256, 0, stream>>>(counts, row_start, bsum, N);
  scan_tops<<<1, 64, 0, stream>>>(bsum, nscan);
  scan_add<<<nscan - 1, 256, 0, stream>>>(row_start, bsum, N);
  csr_init<<<(N + 255) / 256, 256, 0, stream>>>(row_start, fill_pos, csr_src, N);
  csr_scatter<<<(E + 255) / 256, 256, 0, stream>>>(esrc, edst, fill_pos, csr_src, E);

  const int nrb = (N + 127) / 128;
  const int gblocks = ((nrb + 7) / 8) * 32;  // XCD-swizzled flat grid
  const int fblocks = (N * 64 + 255) / 256;

  // layer 1 (K=128)
  gemm_fused<128><<<gblocks, 256, 0, stream>>>(xhiL1, xloL1, w1hi, w1lo, bl[0], br[0], xlB, xrB, N, nrb);
  gat_fused<<<fblocks, 256, 0, stream>>>(xlB, xrB, row_start, csr_src, att[0], bo[0],
                                         xhiL, xloL, N, 1);
  // layer 2 (K=256)
  gemm_fused<256><<<gblocks, 256, 0, stream>>>(xhiL, xloL, w2hi, w2lo, bl[1], br[1], xlB, xrB, N, nrb);
  gat_fused<<<fblocks, 256, 0, stream>>>(xlB, xrB, row_start, csr_src, att[1], bo[1],
                                         xhiL, xloL, N, 1);
  // layer 3 (K=256), bf16 out for pooling
  gemm_fused<256><<<gblocks, 256, 0, stream>>>(xhiL, xloL, w3hi, w3lo, bl[2], br[2], xlB, xrB, N, nrb);
  gat_fused<<<fblocks, 256, 0, stream>>>(xlB, xrB, row_start, csr_src, att[2], bo[2],
                                         h3B, nullptr, N, 2);

  pool_direct<<<NGRAPH, 256, 0, stream>>>(h3B, batch, (float*)d_out, N);
}

// Round 10
// 647.969 us; speedup vs baseline: 1.2358x; 1.2358x over previous
//
#include <hip/hip_runtime.h>

#define HEADS 4
#define CH 64
#define HC 256
#define NGRAPH 32
#define NEG_ATT 0.2f
#define NEG_ACT 0.01f

typedef __attribute__((ext_vector_type(8))) short bf16x8;
typedef __attribute__((ext_vector_type(4))) float f32x4;
typedef __attribute__((ext_vector_type(2))) float f32x2;

typedef __attribute__((address_space(3))) unsigned int lds_u32;
typedef const __attribute__((address_space(1))) unsigned int glob_u32;

// async global->LDS, 16B per lane; LDS dest = wave-uniform base + lane*16
__device__ __forceinline__ void gl_lds16(const void* g, void* l) {
  __builtin_amdgcn_global_load_lds((glob_u32*)(uintptr_t)g,
                                   (lds_u32*)(unsigned int)(uintptr_t)l, 16, 0, 0);
}

// split two fp32 into packed hi-bf16 pair and lo-bf16 pair (truncation; lo captures residual)
__device__ __forceinline__ void split2(float a, float b, unsigned& hi, unsigned& lo) {
  unsigned ua = __float_as_uint(a), ub = __float_as_uint(b);
  float la = a - __uint_as_float(ua & 0xFFFF0000u);
  float lb = b - __uint_as_float(ub & 0xFFFF0000u);
  hi = __builtin_amdgcn_perm(ub, ua, 0x07060302u);  // [hi16(b) : hi16(a)]
  lo = __builtin_amdgcn_perm(__float_as_uint(lb), __float_as_uint(la), 0x07060302u);
}

// round-to-nearest-even fp32 -> bf16 (low 16 bits)
__device__ __forceinline__ unsigned rtn_bf16(float f) {
  unsigned u = __float_as_uint(f);
  return (u + 0x7FFFu + ((u >> 16) & 1u)) >> 16;
}
__device__ __forceinline__ unsigned rtn_pack2(float a, float b) {
  return (rtn_bf16(b) << 16) | rtn_bf16(a);
}

// ---------- conversions ----------
__global__ __launch_bounds__(256) void convert_x(
    const float* __restrict__ X, unsigned short* __restrict__ xhi,
    unsigned short* __restrict__ xlo, int total4) {
  int g = blockIdx.x * 256 + threadIdx.x;
  if (g >= total4) return;
  float4 v = *(const float4*)&X[(size_t)g * 4];
  uint2 h2, l2;
  split2(v.x, v.y, h2.x, l2.x);
  split2(v.z, v.w, h2.y, l2.y);
  *(uint2*)&xhi[(size_t)g * 4] = h2;
  *(uint2*)&xlo[(size_t)g * 4] = l2;
}

// All three W' = [Wl; Wr] (512 x K) -> MFMA-fragment-ordered hi/lo planes, one dispatch.
__device__ __forceinline__ void conv_w_one(
    int g, const float* Wl, const float* Wr, int K,
    unsigned short* wfhi, unsigned short* wflo) {
  int lane = g & 63;
  int ct = (g >> 6) & 31;
  int kb = g >> 11;
  int col = ct * 16 + (lane & 15);
  int k = kb * 32 + (lane >> 4) * 8;
  const float* src = (col < HC) ? &Wl[(size_t)col * K + k] : &Wr[(size_t)(col - HC) * K + k];
  float4 v0 = *(const float4*)src;
  float4 v1 = *(const float4*)(src + 4);
  uint4 hq, lq;
  split2(v0.x, v0.y, hq.x, lq.x);
  split2(v0.z, v0.w, hq.y, lq.y);
  split2(v1.x, v1.y, hq.z, lq.z);
  split2(v1.z, v1.w, hq.w, lq.w);
  *(uint4*)&wfhi[(size_t)g * 8] = hq;
  *(uint4*)&wflo[(size_t)g * 8] = lq;
}

__global__ __launch_bounds__(256) void convert_w_all(
    const float* __restrict__ Wl1, const float* __restrict__ Wr1,
    unsigned short* __restrict__ w1hi, unsigned short* __restrict__ w1lo,
    const float* __restrict__ Wl2, const float* __restrict__ Wr2,
    unsigned short* __restrict__ w2hi, unsigned short* __restrict__ w2lo,
    const float* __restrict__ Wl3, const float* __restrict__ Wr3,
    unsigned short* __restrict__ w3hi, unsigned short* __restrict__ w3lo) {
  int g = blockIdx.x * 256 + threadIdx.x;
  if (g < 8192) conv_w_one(g, Wl1, Wr1, 128, w1hi, w1lo);
  else if (g < 8192 + 16384) conv_w_one(g - 8192, Wl2, Wr2, 256, w2hi, w2lo);
  else conv_w_one(g - 8192 - 16384, Wl3, Wr3, 256, w3hi, w3lo);
}

// ---------- MFMA GEMM: [xl(bf16) | xr(bf16)] = X(hi/lo) @ W'(hi/lo)^T + bias ----------
template <int K>
__global__ __launch_bounds__(256) void gemm_fused(
    const unsigned short* __restrict__ xhi, const unsigned short* __restrict__ xlo,
    const unsigned short* __restrict__ wfhi, const unsigned short* __restrict__ wflo,
    const float* __restrict__ bl, const float* __restrict__ br,
    unsigned short* __restrict__ Y1, unsigned short* __restrict__ Y2, int N, int nrb) {
  constexpr int nkb = K >> 5;
  __shared__ unsigned short Ah[2][128][32];
  __shared__ unsigned short Al[2][128][32];

  // XCD swizzle: f = (rb%8) + 8*(cb + 4*(rb/8)) -> 4 col-siblings land on one XCD
  const int f = blockIdx.x;
  const int rb = (f & 7) + 8 * (f >> 5);
  const int cb = (f >> 3) & 3;
  if (rb >= nrb) return;

  const int tid = threadIdx.x;
  const int wave = tid >> 6;
  const int lane = tid & 63;
  const int quad = lane >> 4;
  const int l16 = lane & 15;
  const int wr = (wave >> 1) * 64;
  const int wc = (wave & 1) * 64;
  const int row0 = rb * 128;
  const int col0 = cb * 128;
  const int ctg0 = cb * 8 + (wave & 1) * 4;

  const int c0 = tid, c1 = tid + 256;
  const int r0g = row0 + (c0 >> 2), r1g = row0 + (c1 >> 2);
  const int ko0 = (c0 & 3) * 8, ko1 = (c1 & 3) * 8;
  const int gr0 = (r0g < N) ? r0g : N - 1;
  const int gr1 = (r1g < N) ? r1g : N - 1;

  f32x4 acc[4][4];
#pragma unroll
  for (int i = 0; i < 4; i++)
#pragma unroll
    for (int j = 0; j < 4; j++) acc[i][j] = (f32x4){0.f, 0.f, 0.f, 0.f};

  {
    size_t ga0 = (size_t)gr0 * K + ko0;
    size_t ga1 = (size_t)gr1 * K + ko1;
    gl_lds16(&xhi[ga0], &Ah[0][c0 >> 2][ko0]);
    gl_lds16(&xlo[ga0], &Al[0][c0 >> 2][ko0]);
    gl_lds16(&xhi[ga1], &Ah[0][c1 >> 2][ko1]);
    gl_lds16(&xlo[ga1], &Al[0][c1 >> 2][ko1]);
  }

#pragma unroll
  for (int kb = 0; kb < nkb; kb++) {
    const int cur = kb & 1, nxt = cur ^ 1;
    bf16x8 bhi[4], blo[4];
#pragma unroll
    for (int j = 0; j < 4; j++) {
      size_t ci = ((size_t)kb * 32 + ctg0 + j) * 64 + lane;
      bhi[j] = *(const bf16x8*)&wfhi[ci * 8];
      blo[j] = *(const bf16x8*)&wflo[ci * 8];
    }
    __syncthreads();  // drains staging(kb) into cur
    if (kb + 1 < nkb) {
      int k0 = (kb + 1) * 32;
      size_t ga0 = (size_t)gr0 * K + k0 + ko0;
      size_t ga1 = (size_t)gr1 * K + k0 + ko1;
      gl_lds16(&xhi[ga0], &Ah[nxt][c0 >> 2][ko0]);
      gl_lds16(&xlo[ga0], &Al[nxt][c0 >> 2][ko0]);
      gl_lds16(&xhi[ga1], &Ah[nxt][c1 >> 2][ko1]);
      gl_lds16(&xlo[ga1], &Al[nxt][c1 >> 2][ko1]);
    }
    bf16x8 ahi[4], alo[4];
#pragma unroll
    for (int i = 0; i < 4; i++) {
      ahi[i] = *(const bf16x8*)&Ah[cur][wr + i * 16 + l16][quad * 8];
      alo[i] = *(const bf16x8*)&Al[cur][wr + i * 16 + l16][quad * 8];
    }
#pragma unroll
    for (int i = 0; i < 4; i++)
#pragma unroll
      for (int j = 0; j < 4; j++) {
        acc[i][j] = __builtin_amdgcn_mfma_f32_16x16x32_bf16(ahi[i], bhi[j], acc[i][j], 0, 0, 0);
        acc[i][j] = __builtin_amdgcn_mfma_f32_16x16x32_bf16(ahi[i], blo[j], acc[i][j], 0, 0, 0);
        acc[i][j] = __builtin_amdgcn_mfma_f32_16x16x32_bf16(alo[i], bhi[j], acc[i][j], 0, 0, 0);
      }
  }

  // epilogue: D row = quad*4+reg, col = l16; both halves -> bf16 (RTN)
#pragma unroll
  for (int j = 0; j < 4; j++) {
    int colg = col0 + wc + j * 16 + l16;  // 0..511
    unsigned short* Yp = (colg < HC) ? Y1 : Y2;
    int cc = (colg < HC) ? colg : colg - HC;
    float bv = (colg < HC) ? bl[cc] : br[cc];
#pragma unroll
    for (int i = 0; i < 4; i++)
#pragma unroll
      for (int r = 0; r < 4; r++) {
        int row = row0 + wr + i * 16 + quad * 4 + r;
        if (row < N)
          Yp[(size_t)row * HC + cc] = (unsigned short)rtn_bf16(acc[i][j][r] + bv);
      }
  }
}

// ---------- CSR build (csr_src holds BYTE offsets into bf16 xl: src*512) ----------
__global__ __launch_bounds__(256) void hist_dst(
    const int* __restrict__ edst, int* __restrict__ counts, int E) {
  int e = blockIdx.x * 256 + threadIdx.x;
  if (e < E) atomicAdd(&counts[edst[e]], 1);
}

__global__ __launch_bounds__(256) void scan_blocks(
    const int* __restrict__ counts, int* __restrict__ row_start,
    int* __restrict__ bsum, int N) {
  __shared__ int tmp[256];
  int t = threadIdx.x;
  int base = blockIdx.x * 1024 + t * 4;
  int v0 = (base     < N) ? counts[base]     + 1 : 0;
  int v1 = (base + 1 < N) ? counts[base + 1] + 1 : 0;
  int v2 = (base + 2 < N) ? counts[base + 2] + 1 : 0;
  int v3 = (base + 3 < N) ? counts[base + 3] + 1 : 0;
  int c1 = v0 + v1, c2 = c1 + v2, tot = c2 + v3;
  tmp[t] = tot;
  __syncthreads();
  for (int off = 1; off < 256; off <<= 1) {
    int add = (t >= off) ? tmp[t - off] : 0;
    __syncthreads();
    tmp[t] += add;
    __syncthreads();
  }
  int excl = tmp[t] - tot;
  if (base     < N) row_start[base + 1] = excl + v0;
  if (base + 1 < N) row_start[base + 2] = excl + c1;
  if (base + 2 < N) row_start[base + 3] = excl + c2;
  if (base + 3 < N) row_start[base + 4] = excl + tot;
  if (t == 255) bsum[blockIdx.x] = tmp[255];
  if (blockIdx.x == 0 && t == 0) row_start[0] = 0;
}

__global__ void scan_tops(int* __restrict__ bsum, int nb) {
  int lane = threadIdx.x;
  int v = (lane < nb) ? bsum[lane] : 0;
  for (int off = 1; off < 64; off <<= 1) {
    int u = __shfl_up(v, off);
    if (lane >= off) v += u;
  }
  if (lane < nb) bsum[lane] = v;
}

__global__ __launch_bounds__(256) void scan_add(
    int* __restrict__ row_start, const int* __restrict__ bsum, int N) {
  int off = bsum[blockIdx.x];
  int i = (blockIdx.x + 1) * 1024 + threadIdx.x * 4;
#pragma unroll
  for (int k = 0; k < 4; k++)
    if (i + k < N) row_start[i + k + 1] += off;
}

__global__ __launch_bounds__(256) void csr_init(
    const int* __restrict__ row_start, int* __restrict__ fill_pos,
    int* __restrict__ csr_src, int N) {
  int i = blockIdx.x * 256 + threadIdx.x;
  if (i < N) {
    int p = row_start[i];
    csr_src[p] = i << 9;  // self-loop first, byte offset
    fill_pos[i] = p + 1;
  }
}

__global__ __launch_bounds__(256) void csr_scatter(
    const int* __restrict__ esrc, const int* __restrict__ edst,
    int* __restrict__ fill_pos, int* __restrict__ csr_src, int E) {
  int e = blockIdx.x * 256 + threadIdx.x;
  if (e < E) {
    int p = atomicAdd(&fill_pos[edst[e]], 1);
    csr_src[p] = esrc[e] << 9;  // byte offset
  }
}

// ---------- fused GATv2 edge phase: raw-exp softmax (scores bounded), packed f32 ----------
__device__ __forceinline__ void unpk(uint2 q, f32x2& v01, f32x2& v23) {
  v01.x = __uint_as_float(q.x << 16);
  v01.y = __uint_as_float(q.x & 0xFFFF0000u);
  v23.x = __uint_as_float(q.y << 16);
  v23.y = __uint_as_float(q.y & 0xFFFF0000u);
}

__device__ __forceinline__ float edot(f32x2 l01, f32x2 l23, f32x2 r01, f32x2 r23,
                                      f32x2 a01, f32x2 a23) {
  f32x2 t01 = l01 + r01, t23 = l23 + r23;          // v_pk_add_f32
  f32x2 u01 = t01 * NEG_ATT, u23 = t23 * NEG_ATT;  // v_pk_mul_f32
  t01.x = fmaxf(t01.x, u01.x); t01.y = fmaxf(t01.y, u01.y);  // leaky = max(t,0.2t)
  t23.x = fmaxf(t23.x, u23.x); t23.y = fmaxf(t23.y, u23.y);
  f32x2 dv = t01 * a01 + t23 * a23;                // pk_mul + pk_fma
  float d = dv.x + dv.y;
  d += __shfl_xor(d, 1);
  d += __shfl_xor(d, 2);
  d += __shfl_xor(d, 4);
  d += __shfl_xor(d, 8);
  return d;
}

// mode 1: leaky + split to hi/lo planes (layers 1,2). mode 2: bf16 RTN out (layer 3).
__global__ __launch_bounds__(256) void gat_fused(
    const unsigned short* __restrict__ xl, const unsigned short* __restrict__ xr,
    const int* __restrict__ row_start, const int* __restrict__ csr_soff,
    const float* __restrict__ att, const float* __restrict__ bo,
    unsigned short* __restrict__ ohi, unsigned short* __restrict__ olo,
    int N, int mode) {
  int dst = (blockIdx.x * 256 + threadIdx.x) >> 6;
  int lane = threadIdx.x & 63;
  if (dst >= N) return;
  int h = lane >> 4;
  int off = h * CH + (lane & 15) * 4;
  const int loff = off * 2;  // byte offset of this lane's 4 bf16 channels
  const char* xlc = (const char*)xl;
  f32x2 a01 = *(const f32x2*)&att[off];
  f32x2 a23 = *(const f32x2*)&att[off + 2];
  f32x2 r01, r23;
  unpk(*(const uint2*)&xr[(size_t)dst * HC + off], r01, r23);
  f32x2 o01 = {0.f, 0.f}, o23 = {0.f, 0.f};
  float s = 0.f;
  int p = row_start[dst];
  int end = row_start[dst + 1];
  for (; p + 4 <= end; p += 4) {
    int b0 = csr_soff[p + 0] + loff, b1 = csr_soff[p + 1] + loff;
    int b2 = csr_soff[p + 2] + loff, b3 = csr_soff[p + 3] + loff;
    uint2 q0 = *(const uint2*)(xlc + b0);
    uint2 q1 = *(const uint2*)(xlc + b1);
    uint2 q2 = *(const uint2*)(xlc + b2);
    uint2 q3 = *(const uint2*)(xlc + b3);
    f32x2 l0a, l0b, l1a, l1b, l2a, l2b, l3a, l3b;
    unpk(q0, l0a, l0b);
    unpk(q1, l1a, l1b);
    unpk(q2, l2a, l2b);
    unpk(q3, l3a, l3b);
    float e0 = __expf(edot(l0a, l0b, r01, r23, a01, a23));
    float e1 = __expf(edot(l1a, l1b, r01, r23, a01, a23));
    float e2 = __expf(edot(l2a, l2b, r01, r23, a01, a23));
    float e3 = __expf(edot(l3a, l3b, r01, r23, a01, a23));
    s += (e0 + e1) + (e2 + e3);
    o01 = l0a * e0 + o01;
    o01 = l1a * e1 + o01;
    o01 = l2a * e2 + o01;
    o01 = l3a * e3 + o01;
    o23 = l0b * e0 + o23;
    o23 = l1b * e1 + o23;
    o23 = l2b * e2 + o23;
    o23 = l3b * e3 + o23;
  }
  for (; p < end; p++) {
    int b0 = csr_soff[p] + loff;
    uint2 q0 = *(const uint2*)(xlc + b0);
    f32x2 la, lb;
    unpk(q0, la, lb);
    float pe = __expf(edot(la, lb, r01, r23, a01, a23));
    s += pe;
    o01 = la * pe + o01;
    o23 = lb * pe + o23;
  }
  float inv = 1.f / s;
  f32x2 b01 = *(const f32x2*)&bo[off];
  f32x2 b23 = *(const f32x2*)&bo[off + 2];
  f32x2 res01 = o01 * inv + b01;
  f32x2 res23 = o23 * inv + b23;
  if (mode == 1) {
    f32x2 v01 = res01 * NEG_ACT, v23 = res23 * NEG_ACT;
    res01.x = fmaxf(res01.x, v01.x); res01.y = fmaxf(res01.y, v01.y);
    res23.x = fmaxf(res23.x, v23.x); res23.y = fmaxf(res23.y, v23.y);
    uint2 h2, l2;
    split2(res01.x, res01.y, h2.x, l2.x);
    split2(res23.x, res23.y, h2.y, l2.y);
    *(uint2*)&ohi[(size_t)dst * HC + off] = h2;
    *(uint2*)&olo[(size_t)dst * HC + off] = l2;
  } else {
    uint2 pk;
    pk.x = rtn_pack2(res01.x, res01.y);
    pk.y = rtn_pack2(res23.x, res23.y);
    *(uint2*)&ohi[(size_t)dst * HC + off] = pk;
  }
}

// ---------- pooling: proven two-stage (per-block LDS partials + atomics), bf16 input ----------
__global__ __launch_bounds__(256) void pool_partial(
    const unsigned short* __restrict__ h3, const int* __restrict__ batch,
    float* __restrict__ out, int* __restrict__ cnt, int N) {
  __shared__ float part[NGRAPH][HC];
  __shared__ int bsh[256];
  __shared__ int cpart[NGRAPH];
  int j = threadIdx.x;
#pragma unroll
  for (int g = 0; g < NGRAPH; g++) part[g][j] = 0.f;
  if (j < NGRAPH) cpart[j] = 0;
  int n0 = blockIdx.x * 256;
  int nend = min(n0 + 256, N);
  int nj = n0 + j;
  bsh[j] = (nj < N) ? batch[nj] : 0;
  __syncthreads();
  if (nj < nend) atomicAdd(&cpart[bsh[j]], 1);
  for (int n = n0; n < nend; n++) {
    int g = bsh[n - n0];
    unsigned q = h3[(size_t)n * HC + j];
    part[g][j] += __uint_as_float(q << 16);
  }
  __syncthreads();
#pragma unroll
  for (int g = 0; g < NGRAPH; g++) {
    float v = part[g][j];
    if (v != 0.f) atomicAdd(&out[g * HC + j], v);
  }
  if (j < NGRAPH && cpart[j] > 0) atomicAdd(&cnt[j], cpart[j]);
}

__global__ __launch_bounds__(256) void pool_final(
    float* __restrict__ out, const int* __restrict__ cnt) {
  int g = blockIdx.x;
  int j = threadIdx.x;
  float c = (float)max(cnt[g], 1);
  out[g * HC + j] /= c;
}

extern "C" void kernel_launch(void* const* d_in, const int* in_sizes, int n_in,
                              void* d_out, int out_size, void* d_ws, size_t ws_size,
                              hipStream_t stream) {
  const float* x = (const float*)d_in[0];
  const int* ei = (const int*)d_in[1];
  const int* batch = (const int*)d_in[2];
  const int N = in_sizes[2];
  const int E = in_sizes[1] / 2;
  const int Etot = E + N;

  const float* Wl[3] = {(const float*)d_in[3], (const float*)d_in[9], (const float*)d_in[15]};
  const float* bl[3] = {(const float*)d_in[4], (const float*)d_in[10], (const float*)d_in[16]};
  const float* Wr[3] = {(const float*)d_in[5], (const float*)d_in[11], (const float*)d_in[17]};
  const float* br[3] = {(const float*)d_in[6], (const float*)d_in[12], (const float*)d_in[18]};
  const float* att[3] = {(const float*)d_in[7], (const float*)d_in[13], (const float*)d_in[19]};
  const float* bo[3] = {(const float*)d_in[8], (const float*)d_in[14], (const float*)d_in[20]};

  // ws layout
  float* B0 = (float*)d_ws;                 // input planes (all layers) / h3 bf16 (layer 3 out)
  float* B1 = B0 + (size_t)N * HC;          // xl (bf16, half the slot)
  float* B2 = B1 + (size_t)N * HC;          // xr (bf16, half the slot)
  unsigned short* w1hi = (unsigned short*)(B2 + (size_t)N * HC);
  unsigned short* w1lo = w1hi + 512 * 128;
  unsigned short* w2hi = w1lo + 512 * 128;
  unsigned short* w2lo = w2hi + 512 * 256;
  unsigned short* w3hi = w2lo + 512 * 256;
  unsigned short* w3lo = w3hi + 512 * 256;
  int* counts = (int*)(w3lo + 512 * 256);
  int* row_start = counts + N;
  int* bsum = row_start + N + 1;
  int* fill_pos = bsum + 64;
  int* csr_src = fill_pos + N;
  int* cnt = csr_src + Etot;

  unsigned short* xlB = (unsigned short*)B1;
  unsigned short* xrB = (unsigned short*)B2;
  unsigned short* xhiL1 = (unsigned short*)B0;
  unsigned short* xloL1 = xhiL1 + (size_t)N * 128;
  unsigned short* xhiL = (unsigned short*)B0;
  unsigned short* xloL = xhiL + (size_t)N * HC;
  unsigned short* h3B = (unsigned short*)B0;  // layer-3 gat output (planes dead by then)

  const int* esrc = ei;
  const int* edst = ei + E;

  // ---- conversions (2 dispatches) ----
  convert_x<<<(N * 128 / 4 + 255) / 256, 256, 0, stream>>>(x, xhiL1, xloL1, N * 128 / 4);
  convert_w_all<<<(8192 + 16384 + 16384) / 256, 256, 0, stream>>>(
      Wl[0], Wr[0], w1hi, w1lo, Wl[1], Wr[1], w2hi, w2lo, Wl[2], Wr[2], w3hi, w3lo);

  // ---- CSR build ----
  const int nscan = (N + 1023) / 1024;
  (void)hipMemsetAsync(counts, 0, (size_t)N * sizeof(int), stream);
  hist_dst<<<(E + 255) / 256, 256, 0, stream>>>(edst, counts, E);
  scan_blocks<<<nscan, 256, 0, stream>>>(counts, row_start, bsum, N);
  scan_tops<<<1, 64, 0, stream>>>(bsum, nscan);
  scan_add<<<nscan - 1, 256, 0, stream>>>(row_start, bsum, N);
  csr_init<<<(N + 255) / 256, 256, 0, stream>>>(row_start, fill_pos, csr_src, N);
  csr_scatter<<<(E + 255) / 256, 256, 0, stream>>>(esrc, edst, fill_pos, csr_src, E);

  const int nrb = (N + 127) / 128;
  const int gblocks = ((nrb + 7) / 8) * 32;  // XCD-swizzled flat grid
  const int fblocks = (N * 64 + 255) / 256;

  // layer 1 (K=128)
  gemm_fused<128><<<gblocks, 256, 0, stream>>>(xhiL1, xloL1, w1hi, w1lo, bl[0], br[0], xlB, xrB, N, nrb);
  gat_fused<<<fblocks, 256, 0, stream>>>(xlB, xrB, row_start, csr_src, att[0], bo[0],
                                         xhiL, xloL, N, 1);
  // layer 2 (K=256)
  gemm_fused<256><<<gblocks, 256, 0, stream>>>(xhiL, xloL, w2hi, w2lo, bl[1], br[1], xlB, xrB, N, nrb);
  gat_fused<<<fblocks, 256, 0, stream>>>(xlB, xrB, row_start, csr_src, att[1], bo[1],
                                         xhiL, xloL, N, 1);
  // layer 3 (K=256), bf16 out for pooling
  gemm_fused<256><<<gblocks, 256, 0, stream>>>(xhiL, xloL, w3hi, w3lo, bl[2], br[2], xlB, xrB, N, nrb);
  gat_fused<<<fblocks, 256, 0, stream>>>(xlB, xrB, row_start, csr_src, att[2], bo[2],
                                         h3B, nullptr, N, 2);

  (void)hipMemsetAsync(d_out, 0, NGRAPH * HC * sizeof(float), stream);
  (void)hipMemsetAsync(cnt, 0, NGRAPH * sizeof(int), stream);
  pool_partial<<<(N + 255) / 256, 256, 0, stream>>>(h3B, batch, (float*)d_out, cnt, N);
  pool_final<<<NGRAPH, 256, 0, stream>>>((float*)d_out, cnt);
}

// Round 11
// 643.126 us; speedup vs baseline: 1.2451x; 1.0075x over previous
//
#include <hip/hip_runtime.h>

#define HEADS 4
#define CH 64
#define HC 256
#define NGRAPH 32
#define NEG_ATT 0.2f
#define NEG_ACT 0.01f

typedef __attribute__((ext_vector_type(8))) short bf16x8;
typedef __attribute__((ext_vector_type(4))) float f32x4;
typedef __attribute__((ext_vector_type(2))) float f32x2;

typedef __attribute__((address_space(3))) unsigned int lds_u32;
typedef const __attribute__((address_space(1))) unsigned int glob_u32;

// async global->LDS, 16B per lane; LDS dest = wave-uniform base + lane*16
__device__ __forceinline__ void gl_lds16(const void* g, void* l) {
  __builtin_amdgcn_global_load_lds((glob_u32*)(uintptr_t)g,
                                   (lds_u32*)(unsigned int)(uintptr_t)l, 16, 0, 0);
}

// split two fp32 into packed hi-bf16 pair and lo-bf16 pair (truncation; lo captures residual)
__device__ __forceinline__ void split2(float a, float b, unsigned& hi, unsigned& lo) {
  unsigned ua = __float_as_uint(a), ub = __float_as_uint(b);
  float la = a - __uint_as_float(ua & 0xFFFF0000u);
  float lb = b - __uint_as_float(ub & 0xFFFF0000u);
  hi = __builtin_amdgcn_perm(ub, ua, 0x07060302u);  // [hi16(b) : hi16(a)]
  lo = __builtin_amdgcn_perm(__float_as_uint(lb), __float_as_uint(la), 0x07060302u);
}

// round-to-nearest-even fp32 -> bf16 (low 16 bits)
__device__ __forceinline__ unsigned rtn_bf16(float f) {
  unsigned u = __float_as_uint(f);
  return (u + 0x7FFFu + ((u >> 16) & 1u)) >> 16;
}
__device__ __forceinline__ unsigned rtn_pack2(float a, float b) {
  return (rtn_bf16(b) << 16) | rtn_bf16(a);
}

// ---------- conversions ----------
__global__ __launch_bounds__(256) void convert_x(
    const float* __restrict__ X, unsigned short* __restrict__ xhi,
    unsigned short* __restrict__ xlo, int total4) {
  int g = blockIdx.x * 256 + threadIdx.x;
  if (g >= total4) return;
  float4 v = *(const float4*)&X[(size_t)g * 4];
  uint2 h2, l2;
  split2(v.x, v.y, h2.x, l2.x);
  split2(v.z, v.w, h2.y, l2.y);
  *(uint2*)&xhi[(size_t)g * 4] = h2;
  *(uint2*)&xlo[(size_t)g * 4] = l2;
}

// All three W' = [Wl; Wr] (512 x K) -> MFMA-fragment-ordered hi/lo planes, one dispatch.
__device__ __forceinline__ void conv_w_one(
    int g, const float* Wl, const float* Wr, int K,
    unsigned short* wfhi, unsigned short* wflo) {
  int lane = g & 63;
  int ct = (g >> 6) & 31;
  int kb = g >> 11;
  int col = ct * 16 + (lane & 15);
  int k = kb * 32 + (lane >> 4) * 8;
  const float* src = (col < HC) ? &Wl[(size_t)col * K + k] : &Wr[(size_t)(col - HC) * K + k];
  float4 v0 = *(const float4*)src;
  float4 v1 = *(const float4*)(src + 4);
  uint4 hq, lq;
  split2(v0.x, v0.y, hq.x, lq.x);
  split2(v0.z, v0.w, hq.y, lq.y);
  split2(v1.x, v1.y, hq.z, lq.z);
  split2(v1.z, v1.w, hq.w, lq.w);
  *(uint4*)&wfhi[(size_t)g * 8] = hq;
  *(uint4*)&wflo[(size_t)g * 8] = lq;
}

__global__ __launch_bounds__(256) void convert_w_all(
    const float* __restrict__ Wl1, const float* __restrict__ Wr1,
    unsigned short* __restrict__ w1hi, unsigned short* __restrict__ w1lo,
    const float* __restrict__ Wl2, const float* __restrict__ Wr2,
    unsigned short* __restrict__ w2hi, unsigned short* __restrict__ w2lo,
    const float* __restrict__ Wl3, const float* __restrict__ Wr3,
    unsigned short* __restrict__ w3hi, unsigned short* __restrict__ w3lo) {
  int g = blockIdx.x * 256 + threadIdx.x;
  if (g < 8192) conv_w_one(g, Wl1, Wr1, 128, w1hi, w1lo);
  else if (g < 8192 + 16384) conv_w_one(g - 8192, Wl2, Wr2, 256, w2hi, w2lo);
  else conv_w_one(g - 8192 - 16384, Wl3, Wr3, 256, w3hi, w3lo);
}

// ---------- MFMA GEMM: [xl(bf16) | xr(bf16)] = X(hi/lo) @ W'(hi/lo)^T + bias ----------
template <int K>
__global__ __launch_bounds__(256) void gemm_fused(
    const unsigned short* __restrict__ xhi, const unsigned short* __restrict__ xlo,
    const unsigned short* __restrict__ wfhi, const unsigned short* __restrict__ wflo,
    const float* __restrict__ bl, const float* __restrict__ br,
    unsigned short* __restrict__ Y1, unsigned short* __restrict__ Y2, int N, int nrb) {
  constexpr int nkb = K >> 5;
  __shared__ unsigned short Ah[2][128][32];
  __shared__ unsigned short Al[2][128][32];

  // XCD swizzle: f = (rb%8) + 8*(cb + 4*(rb/8)) -> 4 col-siblings land on one XCD
  const int f = blockIdx.x;
  const int rb = (f & 7) + 8 * (f >> 5);
  const int cb = (f >> 3) & 3;
  if (rb >= nrb) return;

  const int tid = threadIdx.x;
  const int wave = tid >> 6;
  const int lane = tid & 63;
  const int quad = lane >> 4;
  const int l16 = lane & 15;
  const int wr = (wave >> 1) * 64;
  const int wc = (wave & 1) * 64;
  const int row0 = rb * 128;
  const int col0 = cb * 128;
  const int ctg0 = cb * 8 + (wave & 1) * 4;

  const int c0 = tid, c1 = tid + 256;
  const int r0g = row0 + (c0 >> 2), r1g = row0 + (c1 >> 2);
  const int ko0 = (c0 & 3) * 8, ko1 = (c1 & 3) * 8;
  const int gr0 = (r0g < N) ? r0g : N - 1;
  const int gr1 = (r1g < N) ? r1g : N - 1;

  f32x4 acc[4][4];
#pragma unroll
  for (int i = 0; i < 4; i++)
#pragma unroll
    for (int j = 0; j < 4; j++) acc[i][j] = (f32x4){0.f, 0.f, 0.f, 0.f};

  {
    size_t ga0 = (size_t)gr0 * K + ko0;
    size_t ga1 = (size_t)gr1 * K + ko1;
    gl_lds16(&xhi[ga0], &Ah[0][c0 >> 2][ko0]);
    gl_lds16(&xlo[ga0], &Al[0][c0 >> 2][ko0]);
    gl_lds16(&xhi[ga1], &Ah[0][c1 >> 2][ko1]);
    gl_lds16(&xlo[ga1], &Al[0][c1 >> 2][ko1]);
  }

#pragma unroll
  for (int kb = 0; kb < nkb; kb++) {
    const int cur = kb & 1, nxt = cur ^ 1;
    bf16x8 bhi[4], blo[4];
#pragma unroll
    for (int j = 0; j < 4; j++) {
      size_t ci = ((size_t)kb * 32 + ctg0 + j) * 64 + lane;
      bhi[j] = *(const bf16x8*)&wfhi[ci * 8];
      blo[j] = *(const bf16x8*)&wflo[ci * 8];
    }
    __syncthreads();  // drains staging(kb) into cur
    if (kb + 1 < nkb) {
      int k0 = (kb + 1) * 32;
      size_t ga0 = (size_t)gr0 * K + k0 + ko0;
      size_t ga1 = (size_t)gr1 * K + k0 + ko1;
      gl_lds16(&xhi[ga0], &Ah[nxt][c0 >> 2][ko0]);
      gl_lds16(&xlo[ga0], &Al[nxt][c0 >> 2][ko0]);
      gl_lds16(&xhi[ga1], &Ah[nxt][c1 >> 2][ko1]);
      gl_lds16(&xlo[ga1], &Al[nxt][c1 >> 2][ko1]);
    }
    bf16x8 ahi[4], alo[4];
#pragma unroll
    for (int i = 0; i < 4; i++) {
      ahi[i] = *(const bf16x8*)&Ah[cur][wr + i * 16 + l16][quad * 8];
      alo[i] = *(const bf16x8*)&Al[cur][wr + i * 16 + l16][quad * 8];
    }
#pragma unroll
    for (int i = 0; i < 4; i++)
#pragma unroll
      for (int j = 0; j < 4; j++) {
        acc[i][j] = __builtin_amdgcn_mfma_f32_16x16x32_bf16(ahi[i], bhi[j], acc[i][j], 0, 0, 0);
        acc[i][j] = __builtin_amdgcn_mfma_f32_16x16x32_bf16(ahi[i], blo[j], acc[i][j], 0, 0, 0);
        acc[i][j] = __builtin_amdgcn_mfma_f32_16x16x32_bf16(alo[i], bhi[j], acc[i][j], 0, 0, 0);
      }
  }

  // epilogue: D row = quad*4+reg, col = l16; both halves -> bf16 (RTN)
#pragma unroll
  for (int j = 0; j < 4; j++) {
    int colg = col0 + wc + j * 16 + l16;  // 0..511
    unsigned short* Yp = (colg < HC) ? Y1 : Y2;
    int cc = (colg < HC) ? colg : colg - HC;
    float bv = (colg < HC) ? bl[cc] : br[cc];
#pragma unroll
    for (int i = 0; i < 4; i++)
#pragma unroll
      for (int r = 0; r < 4; r++) {
        int row = row0 + wr + i * 16 + quad * 4 + r;
        if (row < N)
          Yp[(size_t)row * HC + cc] = (unsigned short)rtn_bf16(acc[i][j][r] + bv);
      }
  }
}

// ---------- CSR build (csr_src holds BYTE offsets into bf16 xl: src*512) ----------
__global__ __launch_bounds__(256) void hist_dst(
    const int* __restrict__ edst, int* __restrict__ counts, int E) {
  int e = blockIdx.x * 256 + threadIdx.x;
  if (e < E) atomicAdd(&counts[edst[e]], 1);
}

__global__ __launch_bounds__(256) void scan_blocks(
    const int* __restrict__ counts, int* __restrict__ row_start,
    int* __restrict__ bsum, int N) {
  __shared__ int tmp[256];
  int t = threadIdx.x;
  int base = blockIdx.x * 1024 + t * 4;
  int v0 = (base     < N) ? counts[base]     + 1 : 0;
  int v1 = (base + 1 < N) ? counts[base + 1] + 1 : 0;
  int v2 = (base + 2 < N) ? counts[base + 2] + 1 : 0;
  int v3 = (base + 3 < N) ? counts[base + 3] + 1 : 0;
  int c1 = v0 + v1, c2 = c1 + v2, tot = c2 + v3;
  tmp[t] = tot;
  __syncthreads();
  for (int off = 1; off < 256; off <<= 1) {
    int add = (t >= off) ? tmp[t - off] : 0;
    __syncthreads();
    tmp[t] += add;
    __syncthreads();
  }
  int excl = tmp[t] - tot;
  if (base     < N) row_start[base + 1] = excl + v0;
  if (base + 1 < N) row_start[base + 2] = excl + c1;
  if (base + 2 < N) row_start[base + 3] = excl + c2;
  if (base + 3 < N) row_start[base + 4] = excl + tot;
  if (t == 255) bsum[blockIdx.x] = tmp[255];
  if (blockIdx.x == 0 && t == 0) row_start[0] = 0;
}

__global__ void scan_tops(int* __restrict__ bsum, int nb) {
  int lane = threadIdx.x;
  int v = (lane < nb) ? bsum[lane] : 0;
  for (int off = 1; off < 64; off <<= 1) {
    int u = __shfl_up(v, off);
    if (lane >= off) v += u;
  }
  if (lane < nb) bsum[lane] = v;
}

__global__ __launch_bounds__(256) void scan_add(
    int* __restrict__ row_start, const int* __restrict__ bsum, int N) {
  int off = bsum[blockIdx.x];
  int i = (blockIdx.x + 1) * 1024 + threadIdx.x * 4;
#pragma unroll
  for (int k = 0; k < 4; k++)
    if (i + k < N) row_start[i + k + 1] += off;
}

__global__ __launch_bounds__(256) void csr_init(
    const int* __restrict__ row_start, int* __restrict__ fill_pos,
    int* __restrict__ csr_src, int N) {
  int i = blockIdx.x * 256 + threadIdx.x;
  if (i < N) {
    int p = row_start[i];
    csr_src[p] = i << 9;  // self-loop first, byte offset
    fill_pos[i] = p + 1;
  }
}

__global__ __launch_bounds__(256) void csr_scatter(
    const int* __restrict__ esrc, const int* __restrict__ edst,
    int* __restrict__ fill_pos, int* __restrict__ csr_src, int E) {
  int e = blockIdx.x * 256 + threadIdx.x;
  if (e < E) {
    int p = atomicAdd(&fill_pos[edst[e]], 1);
    csr_src[p] = esrc[e] << 9;  // byte offset
  }
}

// ---------- fused GATv2 edge phase: 2 edges/wave, 8 ch/lane, raw-exp softmax ----------
__device__ __forceinline__ void unpk8(uint4 q, f32x2& v0, f32x2& v1, f32x2& v2, f32x2& v3) {
  v0.x = __uint_as_float(q.x << 16); v0.y = __uint_as_float(q.x & 0xFFFF0000u);
  v1.x = __uint_as_float(q.y << 16); v1.y = __uint_as_float(q.y & 0xFFFF0000u);
  v2.x = __uint_as_float(q.z << 16); v2.y = __uint_as_float(q.z & 0xFFFF0000u);
  v3.x = __uint_as_float(q.w << 16); v3.y = __uint_as_float(q.w & 0xFFFF0000u);
}

// score for this lane's edge slot: 8 channels/lane, 8 lanes per head, 3-stage reduce
__device__ __forceinline__ float edge8(uint4 q,
    f32x2 r0, f32x2 r1, f32x2 r2, f32x2 r3,
    f32x2 a0, f32x2 a1, f32x2 a2, f32x2 a3,
    f32x2& l0, f32x2& l1, f32x2& l2, f32x2& l3) {
  unpk8(q, l0, l1, l2, l3);
  f32x2 t0 = l0 + r0, t1 = l1 + r1, t2 = l2 + r2, t3 = l3 + r3;
  f32x2 u0 = t0 * NEG_ATT, u1 = t1 * NEG_ATT, u2 = t2 * NEG_ATT, u3 = t3 * NEG_ATT;
  t0.x = fmaxf(t0.x, u0.x); t0.y = fmaxf(t0.y, u0.y);
  t1.x = fmaxf(t1.x, u1.x); t1.y = fmaxf(t1.y, u1.y);
  t2.x = fmaxf(t2.x, u2.x); t2.y = fmaxf(t2.y, u2.y);
  t3.x = fmaxf(t3.x, u3.x); t3.y = fmaxf(t3.y, u3.y);
  f32x2 dv = t0 * a0;
  dv = t1 * a1 + dv;
  dv = t2 * a2 + dv;
  dv = t3 * a3 + dv;
  float d = dv.x + dv.y;
  d += __shfl_xor(d, 1);
  d += __shfl_xor(d, 2);
  d += __shfl_xor(d, 4);
  return d;
}

// mode 1: leaky + split to hi/lo planes (layers 1,2). mode 2: bf16 RTN out (layer 3).
__global__ __launch_bounds__(256) void gat_fused(
    const unsigned short* __restrict__ xl, const unsigned short* __restrict__ xr,
    const int* __restrict__ row_start, const int* __restrict__ csr_soff,
    const float* __restrict__ att, const float* __restrict__ bo,
    unsigned short* __restrict__ ohi, unsigned short* __restrict__ olo,
    int N, int mode) {
  int dst = (blockIdx.x * 256 + threadIdx.x) >> 6;
  int lane = threadIdx.x & 63;
  if (dst >= N) return;
  const int slot = lane >> 5;        // which edge of the pair this lane works on
  const int c8 = (lane & 31) * 8;    // first channel of this lane (8 ch/lane)
  const int loff = c8 * 2;           // byte offset within a 512B bf16 row
  const char* xlc = (const char*)xl;

  f32x2 a0 = *(const f32x2*)&att[c8 + 0];
  f32x2 a1 = *(const f32x2*)&att[c8 + 2];
  f32x2 a2 = *(const f32x2*)&att[c8 + 4];
  f32x2 a3 = *(const f32x2*)&att[c8 + 6];

  uint4 qr = *(const uint4*)((const char*)xr + (size_t)dst * 512 + loff);
  f32x2 r0, r1, r2, r3;
  unpk8(qr, r0, r1, r2, r3);

  f32x2 o0 = {0.f, 0.f}, o1 = {0.f, 0.f}, o2 = {0.f, 0.f}, o3 = {0.f, 0.f};
  float s = 0.f;
  int p = row_start[dst];
  const int end = row_start[dst + 1];

  // main: 4 edges (2 pairs) per iteration, 2 gathers in flight
  for (; p + 4 <= end; p += 4) {
    int iA = csr_soff[p + slot];
    int iB = csr_soff[p + 2 + slot];
    uint4 qA = *(const uint4*)(xlc + iA + loff);
    uint4 qB = *(const uint4*)(xlc + iB + loff);
    f32x2 lA0, lA1, lA2, lA3, lB0, lB1, lB2, lB3;
    float dA = edge8(qA, r0, r1, r2, r3, a0, a1, a2, a3, lA0, lA1, lA2, lA3);
    float dB = edge8(qB, r0, r1, r2, r3, a0, a1, a2, a3, lB0, lB1, lB2, lB3);
    float eA = __expf(dA);
    float eB = __expf(dB);
    s += eA + eB;
    o0 = lA0 * eA + o0; o0 = lB0 * eB + o0;
    o1 = lA1 * eA + o1; o1 = lB1 * eB + o1;
    o2 = lA2 * eA + o2; o2 = lB2 * eB + o2;
    o3 = lA3 * eA + o3; o3 = lB3 * eB + o3;
  }
  // remainder: 1..3 edges, pair-at-a-time with slot masking
  for (; p < end; p += 2) {
    int i = p + slot;
    bool vld = i < end;
    int ii = vld ? i : end - 1;
    uint4 q = *(const uint4*)(xlc + csr_soff[ii] + loff);
    f32x2 l0, l1, l2, l3;
    float d = edge8(q, r0, r1, r2, r3, a0, a1, a2, a3, l0, l1, l2, l3);
    float pe = vld ? __expf(d) : 0.f;
    s += pe;
    o0 = l0 * pe + o0;
    o1 = l1 * pe + o1;
    o2 = l2 * pe + o2;
    o3 = l3 * pe + o3;
  }

  // combine the two edge slots (lane i <-> lane i+32 hold same channels)
  s += __shfl_xor(s, 32);
  o0.x += __shfl_xor(o0.x, 32); o0.y += __shfl_xor(o0.y, 32);
  o1.x += __shfl_xor(o1.x, 32); o1.y += __shfl_xor(o1.y, 32);
  o2.x += __shfl_xor(o2.x, 32); o2.y += __shfl_xor(o2.y, 32);
  o3.x += __shfl_xor(o3.x, 32); o3.y += __shfl_xor(o3.y, 32);

  if (slot != 0) return;  // slot-0 half writes the 8 channels
  float inv = 1.f / s;
  f32x2 b0 = *(const f32x2*)&bo[c8 + 0];
  f32x2 b1 = *(const f32x2*)&bo[c8 + 2];
  f32x2 b2 = *(const f32x2*)&bo[c8 + 4];
  f32x2 b3 = *(const f32x2*)&bo[c8 + 6];
  f32x2 s0 = o0 * inv + b0;
  f32x2 s1 = o1 * inv + b1;
  f32x2 s2 = o2 * inv + b2;
  f32x2 s3 = o3 * inv + b3;
  if (mode == 1) {
    f32x2 w0 = s0 * NEG_ACT, w1 = s1 * NEG_ACT, w2 = s2 * NEG_ACT, w3 = s3 * NEG_ACT;
    s0.x = fmaxf(s0.x, w0.x); s0.y = fmaxf(s0.y, w0.y);
    s1.x = fmaxf(s1.x, w1.x); s1.y = fmaxf(s1.y, w1.y);
    s2.x = fmaxf(s2.x, w2.x); s2.y = fmaxf(s2.y, w2.y);
    s3.x = fmaxf(s3.x, w3.x); s3.y = fmaxf(s3.y, w3.y);
    uint4 hq, lq;
    split2(s0.x, s0.y, hq.x, lq.x);
    split2(s1.x, s1.y, hq.y, lq.y);
    split2(s2.x, s2.y, hq.z, lq.z);
    split2(s3.x, s3.y, hq.w, lq.w);
    *(uint4*)&ohi[(size_t)dst * HC + c8] = hq;
    *(uint4*)&olo[(size_t)dst * HC + c8] = lq;
  } else {
    uint4 pk;
    pk.x = rtn_pack2(s0.x, s0.y);
    pk.y = rtn_pack2(s1.x, s1.y);
    pk.z = rtn_pack2(s2.x, s2.y);
    pk.w = rtn_pack2(s3.x, s3.y);
    *(uint4*)&ohi[(size_t)dst * HC + c8] = pk;
  }
}

// ---------- pooling: proven two-stage (per-block LDS partials + atomics), bf16 input ----------
__global__ __launch_bounds__(256) void pool_partial(
    const unsigned short* __restrict__ h3, const int* __restrict__ batch,
    float* __restrict__ out, int* __restrict__ cnt, int N) {
  __shared__ float part[NGRAPH][HC];
  __shared__ int bsh[256];
  __shared__ int cpart[NGRAPH];
  int j = threadIdx.x;
#pragma unroll
  for (int g = 0; g < NGRAPH; g++) part[g][j] = 0.f;
  if (j < NGRAPH) cpart[j] = 0;
  int n0 = blockIdx.x * 256;
  int nend = min(n0 + 256, N);
  int nj = n0 + j;
  bsh[j] = (nj < N) ? batch[nj] : 0;
  __syncthreads();
  if (nj < nend) atomicAdd(&cpart[bsh[j]], 1);
  for (int n = n0; n < nend; n++) {
    int g = bsh[n - n0];
    unsigned q = h3[(size_t)n * HC + j];
    part[g][j] += __uint_as_float(q << 16);
  }
  __syncthreads();
#pragma unroll
  for (int g = 0; g < NGRAPH; g++) {
    float v = part[g][j];
    if (v != 0.f) atomicAdd(&out[g * HC + j], v);
  }
  if (j < NGRAPH && cpart[j] > 0) atomicAdd(&cnt[j], cpart[j]);
}

__global__ __launch_bounds__(256) void pool_final(
    float* __restrict__ out, const int* __restrict__ cnt) {
  int g = blockIdx.x;
  int j = threadIdx.x;
  float c = (float)max(cnt[g], 1);
  out[g * HC + j] /= c;
}

extern "C" void kernel_launch(void* const* d_in, const int* in_sizes, int n_in,
                              void* d_out, int out_size, void* d_ws, size_t ws_size,
                              hipStream_t stream) {
  const float* x = (const float*)d_in[0];
  const int* ei = (const int*)d_in[1];
  const int* batch = (const int*)d_in[2];
  const int N = in_sizes[2];
  const int E = in_sizes[1] / 2;
  const int Etot = E + N;

  const float* Wl[3] = {(const float*)d_in[3], (const float*)d_in[9], (const float*)d_in[15]};
  const float* bl[3] = {(const float*)d_in[4], (const float*)d_in[10], (const float*)d_in[16]};
  const float* Wr[3] = {(const float*)d_in[5], (const float*)d_in[11], (const float*)d_in[17]};
  const float* br[3] = {(const float*)d_in[6], (const float*)d_in[12], (const float*)d_in[18]};
  const float* att[3] = {(const float*)d_in[7], (const float*)d_in[13], (const float*)d_in[19]};
  const float* bo[3] = {(const float*)d_in[8], (const float*)d_in[14], (const float*)d_in[20]};

  // ws layout
  float* B0 = (float*)d_ws;                 // input planes (all layers) / h3 bf16 (layer 3 out)
  float* B1 = B0 + (size_t)N * HC;          // xl (bf16, half the slot)
  float* B2 = B1 + (size_t)N * HC;          // xr (bf16, half the slot)
  unsigned short* w1hi = (unsigned short*)(B2 + (size_t)N * HC);
  unsigned short* w1lo = w1hi + 512 * 128;
  unsigned short* w2hi = w1lo + 512 * 128;
  unsigned short* w2lo = w2hi + 512 * 256;
  unsigned short* w3hi = w2lo + 512 * 256;
  unsigned short* w3lo = w3hi + 512 * 256;
  int* counts = (int*)(w3lo + 512 * 256);
  int* row_start = counts + N;
  int* bsum = row_start + N + 1;
  int* fill_pos = bsum + 64;
  int* csr_src = fill_pos + N;
  int* cnt = csr_src + Etot;

  unsigned short* xlB = (unsigned short*)B1;
  unsigned short* xrB = (unsigned short*)B2;
  unsigned short* xhiL1 = (unsigned short*)B0;
  unsigned short* xloL1 = xhiL1 + (size_t)N * 128;
  unsigned short* xhiL = (unsigned short*)B0;
  unsigned short* xloL = xhiL + (size_t)N * HC;
  unsigned short* h3B = (unsigned short*)B0;  // layer-3 gat output (planes dead by then)

  const int* esrc = ei;
  const int* edst = ei + E;

  // ---- conversions (2 dispatches) ----
  convert_x<<<(N * 128 / 4 + 255) / 256, 256, 0, stream>>>(x, xhiL1, xloL1, N * 128 / 4);
  convert_w_all<<<(8192 + 16384 + 16384) / 256, 256, 0, stream>>>(
      Wl[0], Wr[0], w1hi, w1lo, Wl[1], Wr[1], w2hi, w2lo, Wl[2], Wr[2], w3hi, w3lo);

  // ---- CSR build ----
  const int nscan = (N + 1023) / 1024;
  (void)hipMemsetAsync(counts, 0, (size_t)N * sizeof(int), stream);
  hist_dst<<<(E + 255) / 256, 256, 0, stream>>>(edst, counts, E);
  scan_blocks<<<nscan, 256, 0, stream>>>(counts, row_start, bsum, N);
  scan_tops<<<1, 64, 0, stream>>>(bsum, nscan);
  scan_add<<<nscan - 1, 256, 0, stream>>>(row_start, bsum, N);
  csr_init<<<(N + 255) / 256, 256, 0, stream>>>(row_start, fill_pos, csr_src, N);
  csr_scatter<<<(E + 255) / 256, 256, 0, stream>>>(esrc, edst, fill_pos, csr_src, E);

  const int nrb = (N + 127) / 128;
  const int gblocks = ((nrb + 7) / 8) * 32;  // XCD-swizzled flat grid
  const int fblocks = (N * 64 + 255) / 256;

  // layer 1 (K=128)
  gemm_fused<128><<<gblocks, 256, 0, stream>>>(xhiL1, xloL1, w1hi, w1lo, bl[0], br[0], xlB, xrB, N, nrb);
  gat_fused<<<fblocks, 256, 0, stream>>>(xlB, xrB, row_start, csr_src, att[0], bo[0],
                                         xhiL, xloL, N, 1);
  // layer 2 (K=256)
  gemm_fused<256><<<gblocks, 256, 0, stream>>>(xhiL, xloL, w2hi, w2lo, bl[1], br[1], xlB, xrB, N, nrb);
  gat_fused<<<fblocks, 256, 0, stream>>>(xlB, xrB, row_start, csr_src, att[1], bo[1],
                                         xhiL, xloL, N, 1);
  // layer 3 (K=256), bf16 out for pooling
  gemm_fused<256><<<gblocks, 256, 0, stream>>>(xhiL, xloL, w3hi, w3lo, bl[2], br[2], xlB, xrB, N, nrb);
  gat_fused<<<fblocks, 256, 0, stream>>>(xlB, xrB, row_start, csr_src, att[2], bo[2],
                                         h3B, nullptr, N, 2);

  (void)hipMemsetAsync(d_out, 0, NGRAPH * HC * sizeof(float), stream);
  (void)hipMemsetAsync(cnt, 0, NGRAPH * sizeof(int), stream);
  pool_partial<<<(N + 255) / 256, 256, 0, stream>>>(h3B, batch, (float*)d_out, cnt, N);
  pool_final<<<NGRAPH, 256, 0, stream>>>((float*)d_out, cnt);
}